// Round 2
// baseline (78.579 us; speedup 1.0000x reference)
//
#include <hip/hip_runtime.h>

#define BATCH   256
#define NCOL    576
#define MROW    144
#define ZLIFT   24
#define NIT     3
#define ROW_DEG 15
#define PKSTR   16                               // pk row stride (int4-friendly)
#define NSCIT   ((MROW/ZLIFT) * (NCOL/ZLIFT) * NIT)  // 432
#define TPB     576                              // 9 waves; == NCOL == 4*MROW
#define CCAP    17   // max column degree <= 17 (proven: R3 cap-17 == R4 exact, bit-identical)
#define CSTR    20   // padded stride, 16B-aligned base (tid*20 words) -> float4 gather;
                     // beat banks (20t+i)%32: lanes 0..7 cover all 32 banks -> conflict-free

// SINGLE fused kernel: one block (576 threads, 9 waves) per frame.
// R1 change: the former build_cols producer kernel is folded in — each block
// rebuilds the packed column table pk_s (144 rows x 16, 9.2 KB) in LDS from H.
// H is 331 KB and L2/L3-resident, so the 256x redundant read is ~85 MB of L2
// traffic (~2.5 us aggregate, overlapped with setup loads); in exchange we
// drop one dependent dispatch + its graph gap + the pk global round-trip +
// all workspace use.
//
// pk build: wave wid owns rows [wid*16, wid*16+16). Per row: 3 int4 segments,
// 4 ballots each, rank = popc(mask & below); ascending column order preserved
// (argmin tie-break requires it). Packs n | ((sidx*NIT)<<16),
// sidx = (m/24)*24 + n/24. Entry 15 of each row is a sentinel (0) so decode
// can int4-load 4 entries per lane.
//
// Decode: each check row owned by 4 ADJACENT LANES (row = tid>>2, sub = tid&3);
// lane sub handles edges k in [4*sub, 4*sub+4) (sub 3: 3 real + 1 sentinel).
// Partial min-2/argmin/sign-product merged with 2 order-aware __shfl_xor steps
// (preserves top_k first-occurrence tie-break). E messages live in fixed-stride
// padded column layout (CSTR=20, CCAP=17): slot = n*20 + atomic rank; pads stay
// 0.0f so the gather is 4x ds_read_b128 + 1x ds_read_b32 per column, tree-sum.
__global__ __launch_bounds__(TPB) void ldpc_fused_kernel(
    const float* __restrict__ r,
    const float* __restrict__ alpha,
    const float* __restrict__ beta,
    const int*   __restrict__ H,
    float*       __restrict__ out)
{
    __shared__ float  r_s[NCOL];
    __shared__ float  colsum[NCOL];
    __shared__ __align__(16) float E_s[NCOL * CSTR];   // 46.1 KB
    __shared__ float2 ab_s[NSCIT];        // interleaved {alpha, beta}
    __shared__ int    cdeg[NCOL];         // atomic rank counters
    __shared__ int    pk_s[MROW * PKSTR]; // 9.2 KB packed column table

    const int b    = blockIdx.x;
    const int tid  = threadIdx.x;
    const int row  = tid >> 2;
    const int sub  = tid & 3;
    const int wid  = tid >> 6;            // wave 0..8
    const int lane = tid & 63;

    // Issue frame-data global loads first so their latency overlaps the
    // pk build and LDS setup below.
    const float rv = r[(size_t)b * NCOL + tid];
    float2 abv;
    if (tid < NSCIT) abv = make_float2(alpha[tid], beta[tid]);

    // ---- pk build (wave wid -> rows wid*16 .. wid*16+15) ----
    // Chunked 4-rows-at-a-time: 12 int4 loads in flight per chunk so L2
    // latency is paid ~4x, not 16x.
    const unsigned long long below = (1ull << lane) - 1ull;
    #pragma unroll
    for (int chunk = 0; chunk < 4; ++chunk) {
        int4 h[4][3];
        #pragma unroll
        for (int rr = 0; rr < 4; ++rr) {
            const int m = wid * 16 + chunk * 4 + rr;
            const int4* row4 = (const int4*)(H + (size_t)m * NCOL);
            #pragma unroll
            for (int r0 = 0; r0 < 3; ++r0) {
                const int vidx = r0 * 64 + lane;   // int4 index in row, 0..143
                h[rr][r0] = make_int4(0, 0, 0, 0);
                if (vidx < NCOL / 4) h[rr][r0] = row4[vidx];
            }
        }
        #pragma unroll
        for (int rr = 0; rr < 4; ++rr) {
            const int m = wid * 16 + chunk * 4 + rr;
            if (lane == 0) pk_s[m * PKSTR + 15] = 0;   // sentinel pad entry
            const int srow = (m / ZLIFT) * (NCOL / ZLIFT);
            int base = 0;
            #pragma unroll
            for (int r0 = 0; r0 < 3; ++r0) {
                const int b0 = h[rr][r0].x != 0, b1 = h[rr][r0].y != 0;
                const int b2 = h[rr][r0].z != 0, b3 = h[rr][r0].w != 0;
                const unsigned long long m0 = __ballot(b0);
                const unsigned long long m1 = __ballot(b1);
                const unsigned long long m2 = __ballot(b2);
                const unsigned long long m3 = __ballot(b3);
                const int cnt_below = __popcll(m0 & below) + __popcll(m1 & below)
                                    + __popcll(m2 & below) + __popcll(m3 & below);
                const int bits[4] = {b0, b1, b2, b3};
                const int n0 = (r0 * 64 + lane) * 4;
                int pref = 0;
                #pragma unroll
                for (int c = 0; c < 4; ++c) {
                    if (bits[c]) {
                        const int idx = base + cnt_below + pref;
                        const int n = n0 + c;
                        if (idx < ROW_DEG)
                            pk_s[m * PKSTR + idx] =
                                n | (((srow + n / ZLIFT) * NIT) << 16);
                        ++pref;
                    }
                }
                base += __popcll(m0) + __popcll(m1)
                      + __popcll(m2) + __popcll(m3);
            }
        }
    }

    // ---- setup: stage inputs, zero E + rank counters (tid == column id) ----
    r_s[tid]  = rv;
    cdeg[tid] = 0;
    {
        float4* E4 = (float4*)E_s;        // NCOL*CSTR/4 = 2880 = 5*576 float4s
        const float4 z4 = make_float4(0.f, 0.f, 0.f, 0.f);
        #pragma unroll
        for (int j = 0; j < CSTR / 4; ++j) E4[j * NCOL + tid] = z4;
    }
    if (tid < NSCIT) ab_s[tid] = abv;
    __syncthreads();   // B1: pk built + staged + zeroed

    // ---- per-lane edge state (<=4 edges); pk now read from LDS ----
    const int4 q = *(const int4*)(&pk_s[row * PKSTR + sub * 4]);
    int pk_r[4] = {q.x, q.y, q.z, q.w};
    float r_r[4], E_r[4];
    int   slot_r[4];
    #pragma unroll
    for (int j = 0; j < 4; ++j) {
        const int kglob = sub * 4 + j;
        const int n = pk_r[j] & 0xFFFF;
        r_r[j] = r_s[n];               // sentinel reads r_s[0]: safe, unused
        E_r[j] = 0.0f;
        if (kglob < ROW_DEG)
            slot_r[j] = n * CSTR + atomicAdd(&cdeg[n], 1);
    }
    // (no barrier: slots register-private; E_s zero completed before B1)

    // ---- iterations ----
    for (int it = 0; it < NIT; ++it) {
        // Check phase: partial scan over own edges, then 2-step shuffle merge.
        float vals[4];
        float min1 = INFINITY, min2 = INFINITY;
        int   kmin = 1 << 30;
        float sprod = 1.0f;
        #pragma unroll
        for (int j = 0; j < 4; ++j) {
            const int kglob = sub * 4 + j;
            const bool val = (kglob < ROW_DEG);
            float v;
            if (it == 0) {
                v = r_r[j];
            } else {
                const int n = pk_r[j] & 0xFFFF;
                v = r_r[j] + colsum[n] - E_r[j];
            }
            vals[j] = v;
            const float av = val ? fabsf(v) : INFINITY;
            const float s = val ? ((v > 0.0f) ? 1.0f : ((v < 0.0f) ? -1.0f : 0.0f))
                                : 1.0f;
            sprod *= s;
            if (av < min1)      { min2 = min1; min1 = av; kmin = kglob; }
            else if (av < min2) { min2 = av; }
        }
        // Hoist alpha/beta LDS reads ABOVE the shuffle merge so their ~120cy
        // latency hides under the 2 merge steps (they don't depend on it).
        float2 ab_e[4];
        #pragma unroll
        for (int j = 0; j < 4; ++j) {
            const int kglob = sub * 4 + j;
            if (kglob < ROW_DEG) ab_e[j] = ab_s[(pk_r[j] >> 16) + it];
        }
        // Order-aware merge across the 4 sub-lanes (lower-k side wins ties ==
        // top_k first-occurrence).
        #pragma unroll
        for (int m = 1; m <= 2; m <<= 1) {
            const float o1 = __shfl_xor(min1, m);
            const float o2 = __shfl_xor(min2, m);
            const int   ok = __shfl_xor(kmin, m);
            const float os = __shfl_xor(sprod, m);
            const bool self_lo = ((sub & m) == 0);
            const float lo1 = self_lo ? min1 : o1;
            const float lo2 = self_lo ? min2 : o2;
            const int   lok = self_lo ? kmin : ok;
            const float hi1 = self_lo ? o1 : min1;
            const float hi2 = self_lo ? o2 : min2;
            const int   hik = self_lo ? ok : kmin;
            if (hi1 < lo1) { min1 = hi1; kmin = hik; min2 = fminf(hi2, lo1); }
            else           { min1 = lo1; kmin = lok; min2 = fminf(lo2, hi1); }
            sprod *= os;
        }
        // Extrinsic messages for own edges.
        #pragma unroll
        for (int j = 0; j < 4; ++j) {
            const int kglob = sub * 4 + j;
            if (kglob < ROW_DEG) {
                const float v = vals[j];
                const float s = (v > 0.0f) ? 1.0f : ((v < 0.0f) ? -1.0f : 0.0f);
                const float eabs = (kglob == kmin) ? min2 : min1;
                float mag = eabs - ab_e[j].y;
                if (mag < 0.0f) mag = 0.0f;
                const float E = ab_e[j].x * (sprod * s) * mag;
                E_r[j] = E;
                E_s[slot_r[j]] = E;
            }
        }
        __syncthreads();   // E_s complete; colsum reads done

        // Variable-node phase: one column per thread. 16B-aligned base
        // (tid*20 words) -> 4x ds_read_b128 + 1x ds_read_b32, pads are
        // exactly +0.0f. Tree-sum keeps the FADD chain ~5 deep.
        // Last iteration fused into output write.
        const float4* b4 = (const float4*)(&E_s[tid * CSTR]);
        const float4 x0 = b4[0];
        const float4 x1 = b4[1];
        const float4 x2 = b4[2];
        const float4 x3 = b4[3];
        const float  x4 = E_s[tid * CSTR + 16];
        const float4 t01 = make_float4(x0.x + x1.x, x0.y + x1.y,
                                       x0.z + x1.z, x0.w + x1.w);
        const float4 t23 = make_float4(x2.x + x3.x, x2.y + x3.y,
                                       x2.z + x3.z, x2.w + x3.w);
        const float4 t = make_float4(t01.x + t23.x, t01.y + t23.y,
                                     t01.z + t23.z, t01.w + t23.w);
        const float sum = ((t.x + t.y) + (t.z + t.w)) + x4;
        if (it < NIT - 1) {
            colsum[tid] = sum;
            __syncthreads();   // colsum complete before next check phase
        } else {
            out[(size_t)b * NCOL + tid] = r_s[tid] + sum;
        }
    }
}

extern "C" void kernel_launch(void* const* d_in, const int* in_sizes, int n_in,
                              void* d_out, int out_size, void* d_ws, size_t ws_size,
                              hipStream_t stream) {
    const float* r     = (const float*)d_in[0];
    const float* alpha = (const float*)d_in[1];
    const float* beta  = (const float*)d_in[2];
    const int*   H     = (const int*)d_in[3];
    float* out = (float*)d_out;
    (void)d_ws; (void)ws_size;   // workspace no longer needed

    ldpc_fused_kernel<<<BATCH, TPB, 0, stream>>>(r, alpha, beta, H, out);
}

// Round 3
// 65.345 us; speedup vs baseline: 1.2025x; 1.2025x over previous
//
#include <hip/hip_runtime.h>

#define BATCH   256
#define NCOL    576
#define MROW    144
#define ZLIFT   24
#define NIT     3
#define ROW_DEG 15
#define PKSTR   16                               // pk row stride (int4-friendly)
#define NSCIT   ((MROW/ZLIFT) * (NCOL/ZLIFT) * NIT)  // 432
#define TPB     576                              // 9 waves; == NCOL == 4*MROW
#define CCAP    17   // max column degree <= 17 (proven: R3 cap-17 == R4 exact, bit-identical)
#define CSTR    20   // padded stride, 16B-aligned base (tid*20 words) -> float4 gather;
                     // beat banks (20t+i)%32: lanes 0..7 cover all 32 banks -> conflict-free

// Kernel 1: one wave per check row. int4 loads + 4-ballot rank computation;
// ascending column order preserved (argmin tie-break needs it).
// Packs n | ((sidx*NIT)<<16), sidx=(m/24)*24+n/24, at row stride PKSTR=16.
// Entry 15 of each row is a sentinel (0) so decode can safely int4-load it.
// All three H int4 loads are issued before any ballot work so global latency
// overlaps nothing-but-itself once instead of 3x.
// NOTE (R2 post-mortem): do NOT fuse this into the decode kernel — per-block
// redundant rebuild (16 serial rows/wave + 256x H re-read) cost +13 us.
__global__ __launch_bounds__(256) void build_cols_kernel(
    const int* __restrict__ H, int* __restrict__ pk)
{
    const int wave = (blockIdx.x * blockDim.x + threadIdx.x) >> 6;
    const int lane = threadIdx.x & 63;
    if (wave >= MROW) return;
    const int4* row4 = (const int4*)(H + (size_t)wave * NCOL);
    const int srow = (wave / ZLIFT) * (NCOL / ZLIFT);
    const unsigned long long below = (1ull << lane) - 1ull;
    if (lane == 0) pk[wave * PKSTR + 15] = 0;   // sentinel pad entry

    // Issue all loads first (independent; overlap HBM/L2 latency once).
    int4 h[3];
    #pragma unroll
    for (int r0 = 0; r0 < 3; ++r0) {
        const int vidx = r0 * 64 + lane;        // int4 index within row, 0..143
        h[r0] = make_int4(0, 0, 0, 0);
        if (vidx < NCOL / 4) h[r0] = row4[vidx];
    }

    int base = 0;
    #pragma unroll
    for (int r0 = 0; r0 < 3; ++r0) {
        const int b0 = h[r0].x != 0, b1 = h[r0].y != 0;
        const int b2 = h[r0].z != 0, b3 = h[r0].w != 0;
        const unsigned long long m0 = __ballot(b0);
        const unsigned long long m1 = __ballot(b1);
        const unsigned long long m2 = __ballot(b2);
        const unsigned long long m3 = __ballot(b3);
        const int cnt_below = __popcll(m0 & below) + __popcll(m1 & below)
                            + __popcll(m2 & below) + __popcll(m3 & below);
        const int bits[4] = {b0, b1, b2, b3};
        const int n0 = (r0 * 64 + lane) * 4;
        int pref = 0;
        #pragma unroll
        for (int c = 0; c < 4; ++c) {
            if (bits[c]) {
                const int idx = base + cnt_below + pref;
                const int n = n0 + c;
                if (idx < ROW_DEG)
                    pk[wave * PKSTR + idx] = n | (((srow + n / ZLIFT) * NIT) << 16);
                ++pref;
            }
        }
        base += __popcll(m0) + __popcll(m1) + __popcll(m2) + __popcll(m3);
    }
}

// Kernel 2: one block (576 threads, 9 waves) per frame; TPB == NCOL.
// Each check row is owned by 4 ADJACENT LANES (row = tid>>2, sub = tid&3);
// lane sub handles edges k in [4*sub, 4*sub+4) (sub 3: 3 real + 1 sentinel).
// Partial min-2/argmin/sign-product merged with 2 order-aware __shfl_xor
// steps (preserves top_k first-occurrence tie-break) — no extra barriers.
// E messages live in fixed-stride padded column layout (CSTR=20, CCAP=17):
// slot = n*20 + atomic rank; pads stay 0.0f so the gather is 4x ds_read_b128
// + 1x ds_read_b32, one column per thread, summed as a tree. (NO LDS fp
// atomics for the sum itself — R10 showed ds fp-atomic serialization loses
// to independent reads.)
__global__ __launch_bounds__(TPB) void ldpc_decode_kernel(
    const float* __restrict__ r,
    const float* __restrict__ alpha,
    const float* __restrict__ beta,
    const int*   __restrict__ pk,
    float*       __restrict__ out)
{
    __shared__ float  r_s[NCOL];
    __shared__ float  colsum[NCOL];
    __shared__ __align__(16) float E_s[NCOL * CSTR];   // 11520 floats = 46.1 KB
    __shared__ float2 ab_s[NSCIT];        // interleaved {alpha, beta}
    __shared__ int    cdeg[NCOL];         // atomic rank counters

    const int b   = blockIdx.x;
    const int tid = threadIdx.x;
    const int row = tid >> 2;
    const int sub = tid & 3;

    // Issue ALL global loads first so HBM/L2 latency overlaps the LDS setup
    // and the barrier (pk load hoisted above B1 — it has no LDS dependence).
    const int4  q  = *(const int4*)(pk + row * PKSTR + sub * 4);
    const float rv = r[(size_t)b * NCOL + tid];
    float2 abv;
    if (tid < NSCIT) abv = make_float2(alpha[tid], beta[tid]);

    // ---- setup: stage inputs, zero E + rank counters (tid == column id) ----
    r_s[tid]  = rv;
    cdeg[tid] = 0;
    {
        float4* E4 = (float4*)E_s;        // NCOL*CSTR/4 = 2880 = 5*576 float4s
        const float4 z4 = make_float4(0.f, 0.f, 0.f, 0.f);
        #pragma unroll
        for (int j = 0; j < CSTR / 4; ++j) E4[j * NCOL + tid] = z4;
    }
    if (tid < NSCIT) ab_s[tid] = abv;
    __syncthreads();   // B1: staged + zeroed

    // ---- per-lane edge state (<=4 edges) ----
    int pk_r[4] = {q.x, q.y, q.z, q.w};
    float r_r[4], E_r[4];
    int   slot_r[4];
    #pragma unroll
    for (int j = 0; j < 4; ++j) {
        const int kglob = sub * 4 + j;
        const int n = pk_r[j] & 0xFFFF;
        r_r[j] = r_s[n];               // sentinel reads r_s[0]: safe, unused
        E_r[j] = 0.0f;
        if (kglob < ROW_DEG)
            slot_r[j] = n * CSTR + atomicAdd(&cdeg[n], 1);
    }
    // (no barrier: slots register-private; E_s zero completed before B1)

    // ---- iterations ----
    for (int it = 0; it < NIT; ++it) {
        // Check phase: partial scan over own edges, then 2-step shuffle merge.
        float vals[4];
        float min1 = INFINITY, min2 = INFINITY;
        int   kmin = 1 << 30;
        float sprod = 1.0f;
        #pragma unroll
        for (int j = 0; j < 4; ++j) {
            const int kglob = sub * 4 + j;
            const bool val = (kglob < ROW_DEG);
            float v;
            if (it == 0) {
                v = r_r[j];
            } else {
                const int n = pk_r[j] & 0xFFFF;
                v = r_r[j] + colsum[n] - E_r[j];
            }
            vals[j] = v;
            const float av = val ? fabsf(v) : INFINITY;
            const float s = val ? ((v > 0.0f) ? 1.0f : ((v < 0.0f) ? -1.0f : 0.0f))
                                : 1.0f;
            sprod *= s;
            if (av < min1)      { min2 = min1; min1 = av; kmin = kglob; }
            else if (av < min2) { min2 = av; }
        }
        // Hoist alpha/beta LDS reads ABOVE the shuffle merge so their ~120cy
        // latency hides under the 2 merge steps (they don't depend on it).
        float2 ab_e[4];
        #pragma unroll
        for (int j = 0; j < 4; ++j) {
            const int kglob = sub * 4 + j;
            if (kglob < ROW_DEG) ab_e[j] = ab_s[(pk_r[j] >> 16) + it];
        }
        // Order-aware merge across the 4 sub-lanes (lower-k side wins ties ==
        // top_k first-occurrence).
        #pragma unroll
        for (int m = 1; m <= 2; m <<= 1) {
            const float o1 = __shfl_xor(min1, m);
            const float o2 = __shfl_xor(min2, m);
            const int   ok = __shfl_xor(kmin, m);
            const float os = __shfl_xor(sprod, m);
            const bool self_lo = ((sub & m) == 0);
            const float lo1 = self_lo ? min1 : o1;
            const float lo2 = self_lo ? min2 : o2;
            const int   lok = self_lo ? kmin : ok;
            const float hi1 = self_lo ? o1 : min1;
            const float hi2 = self_lo ? o2 : min2;
            const int   hik = self_lo ? ok : kmin;
            if (hi1 < lo1) { min1 = hi1; kmin = hik; min2 = fminf(hi2, lo1); }
            else           { min1 = lo1; kmin = lok; min2 = fminf(lo2, hi1); }
            sprod *= os;
        }
        // Extrinsic messages for own edges.
        #pragma unroll
        for (int j = 0; j < 4; ++j) {
            const int kglob = sub * 4 + j;
            if (kglob < ROW_DEG) {
                const float v = vals[j];
                const float s = (v > 0.0f) ? 1.0f : ((v < 0.0f) ? -1.0f : 0.0f);
                const float eabs = (kglob == kmin) ? min2 : min1;
                float mag = eabs - ab_e[j].y;
                if (mag < 0.0f) mag = 0.0f;
                const float E = ab_e[j].x * (sprod * s) * mag;
                E_r[j] = E;
                E_s[slot_r[j]] = E;
            }
        }
        __syncthreads();   // E_s complete; colsum reads done

        // Variable-node phase: one column per thread. 16B-aligned base
        // (tid*20 words) -> 4x ds_read_b128 + 1x ds_read_b32, pads are
        // exactly +0.0f. Tree-sum cuts the serial FADD chain 17 -> ~5 deep.
        // Last iteration fused into output write.
        const float4* b4 = (const float4*)(&E_s[tid * CSTR]);
        const float4 x0 = b4[0];
        const float4 x1 = b4[1];
        const float4 x2 = b4[2];
        const float4 x3 = b4[3];
        const float  x4 = E_s[tid * CSTR + 16];
        const float4 t01 = make_float4(x0.x + x1.x, x0.y + x1.y,
                                       x0.z + x1.z, x0.w + x1.w);
        const float4 t23 = make_float4(x2.x + x3.x, x2.y + x3.y,
                                       x2.z + x3.z, x2.w + x3.w);
        const float4 t = make_float4(t01.x + t23.x, t01.y + t23.y,
                                     t01.z + t23.z, t01.w + t23.w);
        const float sum = ((t.x + t.y) + (t.z + t.w)) + x4;
        if (it < NIT - 1) {
            colsum[tid] = sum;
            __syncthreads();   // colsum complete before next check phase
        } else {
            out[(size_t)b * NCOL + tid] = r_s[tid] + sum;
        }
    }
}

extern "C" void kernel_launch(void* const* d_in, const int* in_sizes, int n_in,
                              void* d_out, int out_size, void* d_ws, size_t ws_size,
                              hipStream_t stream) {
    const float* r     = (const float*)d_in[0];
    const float* alpha = (const float*)d_in[1];
    const float* beta  = (const float*)d_in[2];
    const int*   H     = (const int*)d_in[3];
    float* out = (float*)d_out;
    int*   pk  = (int*)d_ws;   // MROW*PKSTR packed ints

    build_cols_kernel<<<(MROW * 64 + 255) / 256, 256, 0, stream>>>(H, pk);
    ldpc_decode_kernel<<<BATCH, TPB, 0, stream>>>(r, alpha, beta, pk, out);
}